// Round 8
// baseline (200.337 us; speedup 1.0000x reference)
//
#include <hip/hip_runtime.h>

// Problem constants
#define NB 2
#define NH 16
#define SEQ 2048
#define DM 1024
#define HD 64
#define MT (NB * SEQ)   // 4096 rows

typedef __attribute__((ext_vector_type(8))) short bf16x8;   // 8 bf16 = 4 VGPRs
typedef __attribute__((ext_vector_type(4))) float f32x4;    // MFMA 16x16 acc
typedef __attribute__((ext_vector_type(8))) unsigned short ushort8;

__device__ __forceinline__ unsigned short f2bf(float f) {
  union { float f; unsigned u; } v; v.f = f;
  return (unsigned short)((v.u + 0x7fffu + ((v.u >> 16) & 1u)) >> 16);  // RNE
}

// async global->LDS, 16B per lane (m97). LDS dst = wave-uniform base + lane*16.
__device__ __forceinline__ void gld_lds16(const unsigned short* g, unsigned short* l) {
  __builtin_amdgcn_global_load_lds((const __attribute__((address_space(1))) unsigned int*)g,
                                   (__attribute__((address_space(3))) unsigned int*)l, 16, 0, 0);
}

// ---------------- fused fp32 -> bf16 convert (x|Wq|Wk|Wv|Wo -> ws contiguous) ----------------
__global__ __launch_bounds__(256) void cvt_all(const float* __restrict__ x,
                                               const float* __restrict__ wq,
                                               const float* __restrict__ wk,
                                               const float* __restrict__ wv,
                                               const float* __restrict__ wo,
                                               unsigned short* __restrict__ dst) {
  const int XO = (MT * DM) / 8;   // 512K chunks of 8 floats
  const int WO = (DM * DM) / 8;   // 128K chunks
  int i = blockIdx.x * 256 + threadIdx.x;     // 0 .. 1M-1 (exact)
  const float* src; int base;
  if (i < XO)               { src = x;  base = 0; }
  else if (i < XO + WO)     { src = wq; base = XO; }
  else if (i < XO + 2 * WO) { src = wk; base = XO + WO; }
  else if (i < XO + 3 * WO) { src = wv; base = XO + 2 * WO; }
  else                      { src = wo; base = XO + 3 * WO; }
  const float4* s4 = (const float4*)(src) + (size_t)(i - base) * 2;
  float4 f0 = s4[0], f1 = s4[1];
  ushort8 u;
  u[0] = f2bf(f0.x); u[1] = f2bf(f0.y); u[2] = f2bf(f0.z); u[3] = f2bf(f0.w);
  u[4] = f2bf(f1.x); u[5] = f2bf(f1.y); u[6] = f2bf(f1.z); u[7] = f2bf(f1.w);
  *((ushort8*)dst + i) = u;
}

// Q pre-scale: 1/1024^0.25 * log2(e), so softmax is bare exp2
#define QSCALE 0.2550565444f

// ---------------- fused QKV projection: [4096,1024] @ [3072,1024]^T ----------------
// AITER-style operand split: A (x) staged via global_load_lds (block-shared);
// B (weights) loaded DIRECTLY global->VGPR as per-lane dwordx4 fragments.
// Feeds MFMA from two pipes (LDS + L2) instead of LDS alone (the ~900TF cap).
// 128x128 tile, 2 waves; wave w: m in [w*64,w*64+64), all 128 n. D rows = n.
__global__ __launch_bounds__(128, 2) void gemm_qkv(const unsigned short* __restrict__ xb,
                                                   const unsigned short* __restrict__ wcat,
                                                   unsigned short* __restrict__ qb,
                                                   unsigned short* __restrict__ kb,
                                                   unsigned short* __restrict__ vtb) {
  __shared__ unsigned short As[128 * 64];   // XOR-swizzled chunk layout
  int m0 = blockIdx.y * 128, n0 = blockIdx.x * 128;
  int tid = threadIdx.x, lane = tid & 63, l15 = lane & 15, quad = lane >> 4, w = tid >> 6;
  const unsigned short* A = xb + (size_t)m0 * DM;

  // A staging offsets: 1024 chunks per 128x64 tile, 128 threads -> 8 each
  int gofs[8];
#pragma unroll
  for (int it = 0; it < 8; ++it) {
    int c = tid + it * 128;
    int r = c >> 3, pos = c & 7;
    gofs[it] = r * DM + ((pos ^ (r & 7)) * 8);
  }
  // B direct-load row pointers: n-subtile j, lane row = l15, k base = quad*8
  const unsigned short* bptr[8];
#pragma unroll
  for (int j = 0; j < 8; ++j)
    bptr[j] = wcat + (size_t)(n0 + j * 16 + l15) * DM + quad * 8;

  f32x4 acc[8][4];
#pragma unroll
  for (int j = 0; j < 8; ++j)
#pragma unroll
    for (int i = 0; i < 4; ++i) acc[j][i] = (f32x4){0.f, 0.f, 0.f, 0.f};

  for (int k0 = 0; k0 < DM; k0 += 64) {
#pragma unroll
    for (int it = 0; it < 8; ++it)
      gld_lds16(A + k0 + gofs[it], As + (tid + it * 128) * 8);
    // issue all B fragment loads for this k64 (in flight across the barrier drain)
    bf16x8 fb[8][2];
#pragma unroll
    for (int j = 0; j < 8; ++j)
#pragma unroll
      for (int s = 0; s < 2; ++s)
        fb[j][s] = *(const bf16x8*)(bptr[j] + k0 + s * 32);
    __syncthreads();   // A staged
#pragma unroll
    for (int s = 0; s < 2; ++s) {
      bf16x8 fa[4];
#pragma unroll
      for (int i = 0; i < 4; ++i) {
        int row = w * 64 + i * 16 + l15, sw = row & 7;
        fa[i] = *(const bf16x8*)(As + row * 64 + (((quad + 4 * s) ^ sw) * 8));
      }
#pragma unroll
      for (int j = 0; j < 8; ++j)
#pragma unroll
        for (int i = 0; i < 4; ++i)
          acc[j][i] = __builtin_amdgcn_mfma_f32_16x16x32_bf16(fb[j][s], fa[i], acc[j][i], 0, 0, 0);
    }
    __syncthreads();   // readers done before next stage overwrites As
  }

  // epilogue (swapped layout): row quad*4+reg = n-local, col l15 = m-local
  int mat = n0 >> 10;   // block-uniform: 0=Q, 1=K, 2=V
#pragma unroll
  for (int j = 0; j < 8; ++j) {
#pragma unroll
    for (int i = 0; i < 4; ++i) {
      int n = n0 + j * 16 + quad * 4;          // +reg gives 4 consecutive n
      int m = m0 + w * 64 + i * 16 + l15;
      int bi = m >> 11, s = m & 2047;
      int c = n & 1023, h = c >> 6, d0 = c & 63;
      if (mat == 2) {
        // V^T [b][h][d][s]: d varies with reg -> 4 scalar stores (lane-contig in s)
#pragma unroll
        for (int reg = 0; reg < 4; ++reg)
          vtb[((size_t)((bi * NH + h) * HD + d0 + reg)) * SEQ + s] = f2bf(acc[j][i][reg]);
      } else {
        unsigned short* dst = (mat == 0) ? qb : kb;
        float sc = (mat == 0) ? QSCALE : 1.0f;
        ushort4 u;
        u.x = f2bf(acc[j][i][0] * sc); u.y = f2bf(acc[j][i][1] * sc);
        u.z = f2bf(acc[j][i][2] * sc); u.w = f2bf(acc[j][i][3] * sc);
        *(ushort4*)(dst + ((size_t)((bi * NH + h) * SEQ + s)) * HD + d0) = u;
      }
    }
  }
}

// ---------------- flash attention, causal; BQ=128 (8 waves), BKV=128 ----------------
#define LP 136   // P/Q row stride (128 kv cols + 8 pad)
#define LDK 72   // K row stride (64 d + 8 pad)
#define LV 136   // V^T row stride (128 kv cols + 8 pad)

__global__ __launch_bounds__(512, 4) void attn_kernel(const unsigned short* __restrict__ qb,
                                                      const unsigned short* __restrict__ kb,
                                                      const unsigned short* __restrict__ vtb,
                                                      unsigned short* __restrict__ ctx) {
  __shared__ unsigned short Ps[128 * LP];    // Q staging, then P (wave-private rows)
  __shared__ unsigned short Ks[128 * LDK];   // [kv][d]
  __shared__ unsigned short Vts[64 * LV];    // [d][kv]
  int bx = blockIdx.x, h = blockIdx.y, bi = blockIdx.z;
  int qst = bi ? (15 - bx) : bx;   // balance: co-resident pairs sum to const work
  int q0 = qst * 128;
  int tid = threadIdx.x, lane = tid & 63, l15 = lane & 15, quad = lane >> 4, w = tid >> 6;

  const unsigned short* qbase = qb + ((size_t)(bi * NH + h) * SEQ + q0) * HD;
  const unsigned short* kbase = kb + ((size_t)(bi * NH + h) * SEQ) * HD;
  const unsigned short* vbase = vtb + ((size_t)(bi * NH + h) * HD) * SEQ;

  // stage Q tile (128x64) into Ps
  {
    int c = tid, r = c >> 3, cc = (c & 7) * 8;
    *(int4*)(Ps + r * LP + cc) = *(const int4*)(qbase + (size_t)r * HD + cc);
    c = tid + 512; r = c >> 3; cc = (c & 7) * 8;
    *(int4*)(Ps + r * LP + cc) = *(const int4*)(qbase + (size_t)r * HD + cc);
  }
  // prefetch KV tile 0: K 128x64 (2 chunks/thread), V^T 64x128 (2 chunks/thread)
  int kr = tid >> 3, kc = (tid & 7) * 8;
  int vr = tid >> 4, vc = (tid & 15) * 8;
  const unsigned short* kS0 = kbase + (size_t)kr * HD + kc;
  const unsigned short* kS1 = kS0 + (size_t)64 * HD;
  const unsigned short* vS0 = vbase + (size_t)vr * SEQ + vc;
  const unsigned short* vS1 = vS0 + (size_t)32 * SEQ;
  int4 kreg0 = *(const int4*)kS0, kreg1 = *(const int4*)kS1;
  int4 vreg0 = *(const int4*)vS0, vreg1 = *(const int4*)vS1;
  unsigned short* Kd0 = Ks + kr * LDK + kc;
  unsigned short* Kd1 = Kd0 + 64 * LDK;
  unsigned short* Vd0 = Vts + vr * LV + vc;
  unsigned short* Vd1 = Vd0 + 32 * LV;
  __syncthreads();   // Q staged

  // Q fragments hoisted; wave w owns q-rows [w*16, w*16+16)
  bf16x8 aq0 = *(const bf16x8*)(Ps + (w * 16 + l15) * LP + 8 * quad);
  bf16x8 aq1 = *(const bf16x8*)(Ps + (w * 16 + l15) * LP + 32 + 8 * quad);

  // ones A-operand: l = ones-row . P via MFMA (no VALU adds, no epilogue butterfly)
  union { uint4 q; bf16x8 v; } onesu;
  onesu.q = make_uint4(0x3F803F80u, 0x3F803F80u, 0x3F803F80u, 0x3F803F80u);
  const bf16x8 ones = onesu.v;

  // O^T accumulation: Oacc[nd] row quad*4+reg = d-local, col l15 = q-local
  f32x4 Oacc[4];
#pragma unroll
  for (int i = 0; i < 4; ++i) Oacc[i] = (f32x4){0.f, 0.f, 0.f, 0.f};
  f32x4 lacc = (f32x4){0.f, 0.f, 0.f, 0.f};   // all regs identical; col l15 = q-local
  int q0w = q0 + w * 16;
  int nt = qst + 1;
  unsigned short* Prow = Ps + (w * 16 + quad * 4) * LP + l15;  // P writes (C-layout)

  for (int j = 0; j < nt; ++j) {
    __syncthreads();                 // prev tile's readers done
    *(int4*)Kd0 = kreg0; *(int4*)Kd1 = kreg1;
    *(int4*)Vd0 = vreg0; *(int4*)Vd1 = vreg1;
    __syncthreads();                 // tile staged
    if (j + 1 < nt) {                // prefetch j+1, overlaps compute below
      size_t ko = (size_t)(j + 1) * 128 * HD;
      int vo = (j + 1) * 128;
      kreg0 = *(const int4*)(kS0 + ko); kreg1 = *(const int4*)(kS1 + ko);
      vreg0 = *(const int4*)(vS0 + vo); vreg1 = *(const int4*)(vS1 + vo);
    }
    bool diag = (j == nt - 1);
    int ns_hi = diag ? w : 7;        // last S-subtile this wave needs
    int s_hi = ns_hi >> 1;           // PV k-steps kept: 0..s_hi

    if (!diag) {
      // common path: no mask, all 8 subtiles
#pragma unroll
      for (int ns = 0; ns < 8; ++ns) {
        bf16x8 bk0 = *(const bf16x8*)(Ks + (ns * 16 + l15) * LDK + 8 * quad);
        bf16x8 bk1 = *(const bf16x8*)(Ks + (ns * 16 + l15) * LDK + 32 + 8 * quad);
        f32x4 s = (f32x4){0.f, 0.f, 0.f, 0.f};
        s = __builtin_amdgcn_mfma_f32_16x16x32_bf16(aq0, bk0, s, 0, 0, 0);
        s = __builtin_amdgcn_mfma_f32_16x16x32_bf16(aq1, bk1, s, 0, 0, 0);
#pragma unroll
        for (int reg = 0; reg < 4; ++reg) {
          float p = __builtin_amdgcn_exp2f(s[reg]);
          union { float f; unsigned u; } pu; pu.f = p;
          Prow[reg * LP + ns * 16] = (unsigned short)(pu.u >> 16);  // trunc bf16
        }
      }
    } else {
      // diagonal tile: subtiles 0..w, elementwise mask only on subtile w
      int kv0 = j * 128;
#pragma unroll
      for (int ns = 0; ns < 8; ++ns) {
        if (ns > ns_hi) break;       // wave-uniform
        bf16x8 bk0 = *(const bf16x8*)(Ks + (ns * 16 + l15) * LDK + 8 * quad);
        bf16x8 bk1 = *(const bf16x8*)(Ks + (ns * 16 + l15) * LDK + 32 + 8 * quad);
        f32x4 s = (f32x4){0.f, 0.f, 0.f, 0.f};
        s = __builtin_amdgcn_mfma_f32_16x16x32_bf16(aq0, bk0, s, 0, 0, 0);
        s = __builtin_amdgcn_mfma_f32_16x16x32_bf16(aq1, bk1, s, 0, 0, 0);
        bool m = (ns == ns_hi);
#pragma unroll
        for (int reg = 0; reg < 4; ++reg) {
          float xv = s[reg];
          if (m) {
            int kvg = kv0 + ns * 16 + l15;
            int qg = q0w + quad * 4 + reg;
            if (kvg > qg) xv = -INFINITY;
          }
          float p = __builtin_amdgcn_exp2f(xv);
          union { float f; unsigned u; } pu; pu.f = p;
          Prow[reg * LP + ns * 16] = (unsigned short)(pu.u >> 16);
        }
      }
      if (!(ns_hi & 1)) {            // zero the odd sibling subtile PV will read
#pragma unroll
        for (int reg = 0; reg < 4; ++reg)
          Prow[reg * LP + (ns_hi + 1) * 16] = 0;
      }
    }

    // PV (swapped: D[d][q]) + ones-row for l; skip fully-masked k-steps
#pragma unroll
    for (int step = 0; step < 4; ++step) {
      if (step > s_hi) break;        // wave-uniform
      bf16x8 pa = *(const bf16x8*)(Ps + (w * 16 + l15) * LP + 8 * quad + 32 * step);
      lacc = __builtin_amdgcn_mfma_f32_16x16x32_bf16(ones, pa, lacc, 0, 0, 0);
#pragma unroll
      for (int nd = 0; nd < 4; ++nd) {
        bf16x8 bv = *(const bf16x8*)(Vts + (nd * 16 + l15) * LV + 8 * quad + 32 * step);
        Oacc[nd] = __builtin_amdgcn_mfma_f32_16x16x32_bf16(bv, pa, Oacc[nd], 0, 0, 0);
      }
    }
  }

  // epilogue: rl lane-matches O^T (q = l15); ushort4 stores along d
  float rl = 1.0f / lacc[0];
  int s = q0w + l15;
#pragma unroll
  for (int nd = 0; nd < 4; ++nd) {
    ushort4 u;
    u.x = f2bf(Oacc[nd][0] * rl); u.y = f2bf(Oacc[nd][1] * rl);
    u.z = f2bf(Oacc[nd][2] * rl); u.w = f2bf(Oacc[nd][3] * rl);
    *(ushort4*)(ctx + ((size_t)(bi * SEQ + s)) * DM + h * HD + nd * 16 + quad * 4) = u;
  }
}

// ---------------- output projection + bias: A via LDS, B (Wo) direct ----------------
// 128m x 64n tile, 2 waves (w splits m); wave 64m x 64n. Grid 512 = 2 blocks/CU.
__global__ __launch_bounds__(128, 2) void gemm_out(const unsigned short* __restrict__ ctx,
                                                   const unsigned short* __restrict__ wob,
                                                   const float* __restrict__ bo,
                                                   float* __restrict__ out) {
  __shared__ unsigned short As[128 * 64];
  int n0 = blockIdx.x * 64, m0 = blockIdx.y * 128;
  int tid = threadIdx.x, lane = tid & 63, l15 = lane & 15, quad = lane >> 4, w = tid >> 6;
  const unsigned short* A = ctx + (size_t)m0 * DM;

  int gofs[8];
#pragma unroll
  for (int it = 0; it < 8; ++it) {
    int c = tid + it * 128;
    int r = c >> 3, pos = c & 7;
    gofs[it] = r * DM + ((pos ^ (r & 7)) * 8);
  }
  const unsigned short* bptr[4];
#pragma unroll
  for (int j = 0; j < 4; ++j)
    bptr[j] = wob + (size_t)(n0 + j * 16 + l15) * DM + quad * 8;

  f32x4 acc[4][4];
#pragma unroll
  for (int j = 0; j < 4; ++j)
#pragma unroll
    for (int i = 0; i < 4; ++i) acc[j][i] = (f32x4){0.f, 0.f, 0.f, 0.f};

  for (int k0 = 0; k0 < DM; k0 += 64) {
#pragma unroll
    for (int it = 0; it < 8; ++it)
      gld_lds16(A + k0 + gofs[it], As + (tid + it * 128) * 8);
    bf16x8 fb[4][2];
#pragma unroll
    for (int j = 0; j < 4; ++j)
#pragma unroll
      for (int s = 0; s < 2; ++s)
        fb[j][s] = *(const bf16x8*)(bptr[j] + k0 + s * 32);
    __syncthreads();
#pragma unroll
    for (int s = 0; s < 2; ++s) {
      bf16x8 fa[4];
#pragma unroll
      for (int i = 0; i < 4; ++i) {
        int row = w * 64 + i * 16 + l15, sw = row & 7;
        fa[i] = *(const bf16x8*)(As + row * 64 + (((quad + 4 * s) ^ sw) * 8));
      }
#pragma unroll
      for (int j = 0; j < 4; ++j)
#pragma unroll
        for (int i = 0; i < 4; ++i)
          acc[j][i] = __builtin_amdgcn_mfma_f32_16x16x32_bf16(fb[j][s], fa[i], acc[j][i], 0, 0, 0);
    }
    __syncthreads();
  }

  // epilogue (swapped): regs = 4 consecutive n -> float4 stores + float4 bias
#pragma unroll
  for (int j = 0; j < 4; ++j)
#pragma unroll
    for (int i = 0; i < 4; ++i) {
      int n = n0 + j * 16 + quad * 4;
      int m = m0 + w * 64 + i * 16 + l15;
      float4 bv = *(const float4*)(bo + n);
      float4 o;
      o.x = acc[j][i][0] + bv.x; o.y = acc[j][i][1] + bv.y;
      o.z = acc[j][i][2] + bv.z; o.w = acc[j][i][3] + bv.w;
      *(float4*)(out + (size_t)m * DM + n) = o;
    }
}

// ---------------- launch ----------------
extern "C" void kernel_launch(void* const* d_in, const int* in_sizes, int n_in,
                              void* d_out, int out_size, void* d_ws, size_t ws_size,
                              hipStream_t stream) {
  const float* x  = (const float*)d_in[0];
  const float* Wq = (const float*)d_in[1];
  const float* Wk = (const float*)d_in[2];
  const float* Wv = (const float*)d_in[3];
  const float* Wo = (const float*)d_in[4];
  const float* bo = (const float*)d_in[5];
  float* out = (float*)d_out;

  unsigned short* ws = (unsigned short*)d_ws;
  // bf16 workspace: [x(4M) | Wq Wk Wv (3M) | Wo(1M) | Q(4M) | K(4M) | V^T(4M)]; ctx aliases x.
  unsigned short* xb   = ws;
  unsigned short* ctx  = ws;
  unsigned short* wcat = ws + (size_t)MT * DM;
  unsigned short* wob  = wcat + (size_t)3 * DM * DM;
  unsigned short* qb   = wob + (size_t)DM * DM;
  unsigned short* kb   = qb + (size_t)MT * DM;
  unsigned short* vtb  = kb + (size_t)MT * DM;

  int total8 = (MT * DM + 4 * DM * DM) / 8;   // 1M chunks of 8 floats
  cvt_all<<<total8 / 256, 256, 0, stream>>>(x, Wq, Wk, Wv, Wo, ws);

  gemm_qkv<<<dim3(24, 32), 128, 0, stream>>>(xb, wcat, qb, kb, vtb);
  attn_kernel<<<dim3(16, NH, NB), 512, 0, stream>>>(qb, kb, vtb, ctx);
  gemm_out<<<dim3(16, 32), 128, 0, stream>>>(ctx, wob, bo, out);
}

// Round 9
// 167.946 us; speedup vs baseline: 1.1929x; 1.1929x over previous
//
#include <hip/hip_runtime.h>

// Problem constants
#define NB 2
#define NH 16
#define SEQ 2048
#define DM 1024
#define HD 64
#define MT (NB * SEQ)   // 4096 rows

typedef __attribute__((ext_vector_type(8))) short bf16x8;   // 8 bf16 = 4 VGPRs
typedef __attribute__((ext_vector_type(4))) float f32x4;    // MFMA 16x16 acc
typedef __attribute__((ext_vector_type(8))) unsigned short ushort8;

__device__ __forceinline__ unsigned short f2bf(float f) {
  union { float f; unsigned u; } v; v.f = f;
  return (unsigned short)((v.u + 0x7fffu + ((v.u >> 16) & 1u)) >> 16);  // RNE
}

// async global->LDS, 16B per lane (m97). LDS dst = wave-uniform base + lane*16.
__device__ __forceinline__ void gld_lds16(const unsigned short* g, unsigned short* l) {
  __builtin_amdgcn_global_load_lds((const __attribute__((address_space(1))) unsigned int*)g,
                                   (__attribute__((address_space(3))) unsigned int*)l, 16, 0, 0);
}

// ---------------- fused fp32 -> bf16 convert (x|Wq|Wk|Wv|Wo -> ws contiguous) ----------------
__global__ __launch_bounds__(256) void cvt_all(const float* __restrict__ x,
                                               const float* __restrict__ wq,
                                               const float* __restrict__ wk,
                                               const float* __restrict__ wv,
                                               const float* __restrict__ wo,
                                               unsigned short* __restrict__ dst) {
  const int XO = (MT * DM) / 8;   // 512K chunks of 8 floats
  const int WO = (DM * DM) / 8;   // 128K chunks
  int i = blockIdx.x * 256 + threadIdx.x;     // 0 .. 1M-1 (exact)
  const float* src; int base;
  if (i < XO)               { src = x;  base = 0; }
  else if (i < XO + WO)     { src = wq; base = XO; }
  else if (i < XO + 2 * WO) { src = wk; base = XO + WO; }
  else if (i < XO + 3 * WO) { src = wv; base = XO + 2 * WO; }
  else                      { src = wo; base = XO + 3 * WO; }
  const float4* s4 = (const float4*)(src) + (size_t)(i - base) * 2;
  float4 f0 = s4[0], f1 = s4[1];
  ushort8 u;
  u[0] = f2bf(f0.x); u[1] = f2bf(f0.y); u[2] = f2bf(f0.z); u[3] = f2bf(f0.w);
  u[4] = f2bf(f1.x); u[5] = f2bf(f1.y); u[6] = f2bf(f1.z); u[7] = f2bf(f1.w);
  *((ushort8*)dst + i) = u;
}

// Q pre-scale: 1/1024^0.25 * log2(e), so softmax is bare exp2
#define QSCALE 0.2550565444f

// ---------------- fused QKV projection: [4096,1024] @ [3072,1024]^T ----------------
// 128x128 tile, 2 waves; wave w owns m in [w*64, w*64+64), all 128 n (R7 structure).
// Grid mapping: x = m (32), y = n (24) so co-dispatched blocks SHARE the B (weight)
// tile in L2 — R8 counters showed 36 MB FETCH vs 14 MB unique input (L2 thrash).
__global__ __launch_bounds__(128, 2) void gemm_qkv(const unsigned short* __restrict__ xb,
                                                   const unsigned short* __restrict__ wcat,
                                                   unsigned short* __restrict__ qb,
                                                   unsigned short* __restrict__ kb,
                                                   unsigned short* __restrict__ vtb) {
  __shared__ unsigned short As[128 * 64], Bs[128 * 64];   // XOR-swizzled chunk layout
  int m0 = blockIdx.x * 128, n0 = blockIdx.y * 128;
  int tid = threadIdx.x, lane = tid & 63, l15 = lane & 15, quad = lane >> 4, w = tid >> 6;
  const unsigned short* A = xb + (size_t)m0 * DM;
  const unsigned short* B = wcat + (size_t)n0 * DM;

  // staging offsets: 1024 chunks per 128x64 tile, 128 threads -> 8 each
  int gofs[8];
#pragma unroll
  for (int it = 0; it < 8; ++it) {
    int c = tid + it * 128;
    int r = c >> 3, pos = c & 7;
    gofs[it] = r * DM + ((pos ^ (r & 7)) * 8);
  }

  f32x4 acc[8][4];
#pragma unroll
  for (int j = 0; j < 8; ++j)
#pragma unroll
    for (int i = 0; i < 4; ++i) acc[j][i] = (f32x4){0.f, 0.f, 0.f, 0.f};

  for (int k0 = 0; k0 < DM; k0 += 64) {
#pragma unroll
    for (int it = 0; it < 8; ++it)
      gld_lds16(A + k0 + gofs[it], As + (tid + it * 128) * 8);
#pragma unroll
    for (int it = 0; it < 8; ++it)
      gld_lds16(B + k0 + gofs[it], Bs + (tid + it * 128) * 8);
    __syncthreads();
#pragma unroll
    for (int s = 0; s < 2; ++s) {
      bf16x8 fa[4];
#pragma unroll
      for (int i = 0; i < 4; ++i) {
        int row = w * 64 + i * 16 + l15, sw = row & 7;
        fa[i] = *(const bf16x8*)(As + row * 64 + (((quad + 4 * s) ^ sw) * 8));
      }
#pragma unroll
      for (int j = 0; j < 8; ++j) {
        int row = j * 16 + l15, sw = row & 7;
        bf16x8 fb = *(const bf16x8*)(Bs + row * 64 + (((quad + 4 * s) ^ sw) * 8));
#pragma unroll
        for (int i = 0; i < 4; ++i)
          acc[j][i] = __builtin_amdgcn_mfma_f32_16x16x32_bf16(fb, fa[i], acc[j][i], 0, 0, 0);
      }
    }
    __syncthreads();
  }

  // epilogue (swapped layout): row quad*4+reg = n-local, col l15 = m-local
  int mat = n0 >> 10;   // block-uniform: 0=Q, 1=K, 2=V
#pragma unroll
  for (int j = 0; j < 8; ++j) {
#pragma unroll
    for (int i = 0; i < 4; ++i) {
      int n = n0 + j * 16 + quad * 4;          // +reg gives 4 consecutive n
      int m = m0 + w * 64 + i * 16 + l15;
      int bi = m >> 11, s = m & 2047;
      int c = n & 1023, h = c >> 6, d0 = c & 63;
      if (mat == 2) {
        // V^T [b][h][d][s]: d varies with reg -> 4 scalar stores (lane-contig in s)
#pragma unroll
        for (int reg = 0; reg < 4; ++reg)
          vtb[((size_t)((bi * NH + h) * HD + d0 + reg)) * SEQ + s] = f2bf(acc[j][i][reg]);
      } else {
        unsigned short* dst = (mat == 0) ? qb : kb;
        float sc = (mat == 0) ? QSCALE : 1.0f;
        ushort4 u;
        u.x = f2bf(acc[j][i][0] * sc); u.y = f2bf(acc[j][i][1] * sc);
        u.z = f2bf(acc[j][i][2] * sc); u.w = f2bf(acc[j][i][3] * sc);
        *(ushort4*)(dst + ((size_t)((bi * NH + h) * SEQ + s)) * HD + d0) = u;
      }
    }
  }
}

// ---------------- flash attention, causal; BQ=128 (8 waves), BKV=128 ----------------
#define LP 136   // P/Q row stride (128 kv cols + 8 pad)
#define LDK 72   // K row stride (64 d + 8 pad)
#define LV 136   // V^T row stride (128 kv cols + 8 pad)

__global__ __launch_bounds__(512, 4) void attn_kernel(const unsigned short* __restrict__ qb,
                                                      const unsigned short* __restrict__ kb,
                                                      const unsigned short* __restrict__ vtb,
                                                      unsigned short* __restrict__ ctx) {
  __shared__ unsigned short Ps[128 * LP];    // Q staging, then P (wave-private rows)
  __shared__ unsigned short Ks[128 * LDK];   // [kv][d]
  __shared__ unsigned short Vts[64 * LV];    // [d][kv]
  int bx = blockIdx.x, h = blockIdx.y, bi = blockIdx.z;
  int qst = bi ? (15 - bx) : bx;   // balance: co-resident pairs sum to const work
  int q0 = qst * 128;
  int tid = threadIdx.x, lane = tid & 63, l15 = lane & 15, quad = lane >> 4, w = tid >> 6;

  const unsigned short* qbase = qb + ((size_t)(bi * NH + h) * SEQ + q0) * HD;
  const unsigned short* kbase = kb + ((size_t)(bi * NH + h) * SEQ) * HD;
  const unsigned short* vbase = vtb + ((size_t)(bi * NH + h) * HD) * SEQ;

  // stage Q tile (128x64) into Ps
  {
    int c = tid, r = c >> 3, cc = (c & 7) * 8;
    *(int4*)(Ps + r * LP + cc) = *(const int4*)(qbase + (size_t)r * HD + cc);
    c = tid + 512; r = c >> 3; cc = (c & 7) * 8;
    *(int4*)(Ps + r * LP + cc) = *(const int4*)(qbase + (size_t)r * HD + cc);
  }
  // prefetch KV tile 0: K 128x64 (2 chunks/thread), V^T 64x128 (2 chunks/thread)
  int kr = tid >> 3, kc = (tid & 7) * 8;
  int vr = tid >> 4, vc = (tid & 15) * 8;
  const unsigned short* kS0 = kbase + (size_t)kr * HD + kc;
  const unsigned short* kS1 = kS0 + (size_t)64 * HD;
  const unsigned short* vS0 = vbase + (size_t)vr * SEQ + vc;
  const unsigned short* vS1 = vS0 + (size_t)32 * SEQ;
  int4 kreg0 = *(const int4*)kS0, kreg1 = *(const int4*)kS1;
  int4 vreg0 = *(const int4*)vS0, vreg1 = *(const int4*)vS1;
  unsigned short* Kd0 = Ks + kr * LDK + kc;
  unsigned short* Kd1 = Kd0 + 64 * LDK;
  unsigned short* Vd0 = Vts + vr * LV + vc;
  unsigned short* Vd1 = Vd0 + 32 * LV;
  __syncthreads();   // Q staged

  // Q fragments hoisted; wave w owns q-rows [w*16, w*16+16)
  bf16x8 aq0 = *(const bf16x8*)(Ps + (w * 16 + l15) * LP + 8 * quad);
  bf16x8 aq1 = *(const bf16x8*)(Ps + (w * 16 + l15) * LP + 32 + 8 * quad);

  // ones A-operand: l = ones-row . P via MFMA (no VALU adds, no epilogue butterfly)
  union { uint4 q; bf16x8 v; } onesu;
  onesu.q = make_uint4(0x3F803F80u, 0x3F803F80u, 0x3F803F80u, 0x3F803F80u);
  const bf16x8 ones = onesu.v;

  // O^T accumulation: Oacc[nd] row quad*4+reg = d-local, col l15 = q-local
  f32x4 Oacc[4];
#pragma unroll
  for (int i = 0; i < 4; ++i) Oacc[i] = (f32x4){0.f, 0.f, 0.f, 0.f};
  f32x4 lacc = (f32x4){0.f, 0.f, 0.f, 0.f};   // all regs identical; col l15 = q-local
  int q0w = q0 + w * 16;
  int nt = qst + 1;
  unsigned short* Prow = Ps + (w * 16 + quad * 4) * LP + l15;  // P writes (C-layout)

  for (int j = 0; j < nt; ++j) {
    __syncthreads();                 // prev tile's readers done
    *(int4*)Kd0 = kreg0; *(int4*)Kd1 = kreg1;
    *(int4*)Vd0 = vreg0; *(int4*)Vd1 = vreg1;
    __syncthreads();                 // tile staged
    if (j + 1 < nt) {                // prefetch j+1, overlaps compute below
      size_t ko = (size_t)(j + 1) * 128 * HD;
      int vo = (j + 1) * 128;
      kreg0 = *(const int4*)(kS0 + ko); kreg1 = *(const int4*)(kS1 + ko);
      vreg0 = *(const int4*)(vS0 + vo); vreg1 = *(const int4*)(vS1 + vo);
    }
    bool diag = (j == nt - 1);
    int ns_hi = diag ? w : 7;        // last S-subtile this wave needs
    int s_hi = ns_hi >> 1;           // PV k-steps kept: 0..s_hi

    if (!diag) {
      // common path: no mask, all 8 subtiles
#pragma unroll
      for (int ns = 0; ns < 8; ++ns) {
        bf16x8 bk0 = *(const bf16x8*)(Ks + (ns * 16 + l15) * LDK + 8 * quad);
        bf16x8 bk1 = *(const bf16x8*)(Ks + (ns * 16 + l15) * LDK + 32 + 8 * quad);
        f32x4 s = (f32x4){0.f, 0.f, 0.f, 0.f};
        s = __builtin_amdgcn_mfma_f32_16x16x32_bf16(aq0, bk0, s, 0, 0, 0);
        s = __builtin_amdgcn_mfma_f32_16x16x32_bf16(aq1, bk1, s, 0, 0, 0);
#pragma unroll
        for (int reg = 0; reg < 4; ++reg) {
          float p = __builtin_amdgcn_exp2f(s[reg]);
          union { float f; unsigned u; } pu; pu.f = p;
          Prow[reg * LP + ns * 16] = (unsigned short)(pu.u >> 16);  // trunc bf16
        }
      }
    } else {
      // diagonal tile: subtiles 0..w, elementwise mask only on subtile w
      int kv0 = j * 128;
#pragma unroll
      for (int ns = 0; ns < 8; ++ns) {
        if (ns > ns_hi) break;       // wave-uniform
        bf16x8 bk0 = *(const bf16x8*)(Ks + (ns * 16 + l15) * LDK + 8 * quad);
        bf16x8 bk1 = *(const bf16x8*)(Ks + (ns * 16 + l15) * LDK + 32 + 8 * quad);
        f32x4 s = (f32x4){0.f, 0.f, 0.f, 0.f};
        s = __builtin_amdgcn_mfma_f32_16x16x32_bf16(aq0, bk0, s, 0, 0, 0);
        s = __builtin_amdgcn_mfma_f32_16x16x32_bf16(aq1, bk1, s, 0, 0, 0);
        bool m = (ns == ns_hi);
#pragma unroll
        for (int reg = 0; reg < 4; ++reg) {
          float xv = s[reg];
          if (m) {
            int kvg = kv0 + ns * 16 + l15;
            int qg = q0w + quad * 4 + reg;
            if (kvg > qg) xv = -INFINITY;
          }
          float p = __builtin_amdgcn_exp2f(xv);
          union { float f; unsigned u; } pu; pu.f = p;
          Prow[reg * LP + ns * 16] = (unsigned short)(pu.u >> 16);
        }
      }
      if (!(ns_hi & 1)) {            // zero the odd sibling subtile PV will read
#pragma unroll
        for (int reg = 0; reg < 4; ++reg)
          Prow[reg * LP + (ns_hi + 1) * 16] = 0;
      }
    }

    // PV (swapped: D[d][q]) + ones-row for l; skip fully-masked k-steps
#pragma unroll
    for (int step = 0; step < 4; ++step) {
      if (step > s_hi) break;        // wave-uniform
      bf16x8 pa = *(const bf16x8*)(Ps + (w * 16 + l15) * LP + 8 * quad + 32 * step);
      lacc = __builtin_amdgcn_mfma_f32_16x16x32_bf16(ones, pa, lacc, 0, 0, 0);
#pragma unroll
      for (int nd = 0; nd < 4; ++nd) {
        bf16x8 bv = *(const bf16x8*)(Vts + (nd * 16 + l15) * LV + 8 * quad + 32 * step);
        Oacc[nd] = __builtin_amdgcn_mfma_f32_16x16x32_bf16(bv, pa, Oacc[nd], 0, 0, 0);
      }
    }
  }

  // epilogue: rl lane-matches O^T (q = l15); ushort4 stores along d
  float rl = 1.0f / lacc[0];
  int s = q0w + l15;
#pragma unroll
  for (int nd = 0; nd < 4; ++nd) {
    ushort4 u;
    u.x = f2bf(Oacc[nd][0] * rl); u.y = f2bf(Oacc[nd][1] * rl);
    u.z = f2bf(Oacc[nd][2] * rl); u.w = f2bf(Oacc[nd][3] * rl);
    *(ushort4*)(ctx + ((size_t)(bi * SEQ + s)) * DM + h * HD + nd * 16 + quad * 4) = u;
  }
}

// ---------------- output projection + bias: 64x128 tile, 4 waves (wave 32m x 64n) ---------
// Grid mapping x = m (64), y = n (8): co-dispatched blocks share the Wo tile in L2.
__global__ __launch_bounds__(256, 2) void gemm_out(const unsigned short* __restrict__ ctx,
                                                   const unsigned short* __restrict__ wob,
                                                   const float* __restrict__ bo,
                                                   float* __restrict__ out) {
  __shared__ unsigned short As[64 * 64], Bs[128 * 64];
  int m0 = blockIdx.x * 64, n0 = blockIdx.y * 128;
  int tid = threadIdx.x, lane = tid & 63, l15 = lane & 15, quad = lane >> 4, w = tid >> 6;
  int wm = (w >> 1) * 32, wn = (w & 1) * 64;
  const unsigned short* A = ctx + (size_t)m0 * DM;
  const unsigned short* B = wob + (size_t)n0 * DM;

  int goA[2], goB[4];
#pragma unroll
  for (int it = 0; it < 2; ++it) {
    int c = tid + it * 256, r = c >> 3, pos = c & 7;
    goA[it] = r * DM + ((pos ^ (r & 7)) * 8);
  }
#pragma unroll
  for (int it = 0; it < 4; ++it) {
    int c = tid + it * 256, r = c >> 3, pos = c & 7;
    goB[it] = r * DM + ((pos ^ (r & 7)) * 8);
  }

  f32x4 acc[4][2];
#pragma unroll
  for (int j = 0; j < 4; ++j)
#pragma unroll
    for (int i = 0; i < 2; ++i) acc[j][i] = (f32x4){0.f, 0.f, 0.f, 0.f};

  for (int k0 = 0; k0 < DM; k0 += 64) {
#pragma unroll
    for (int it = 0; it < 2; ++it)
      gld_lds16(A + k0 + goA[it], As + (tid + it * 256) * 8);
#pragma unroll
    for (int it = 0; it < 4; ++it)
      gld_lds16(B + k0 + goB[it], Bs + (tid + it * 256) * 8);
    __syncthreads();
#pragma unroll
    for (int s = 0; s < 2; ++s) {
      bf16x8 fa[2];
#pragma unroll
      for (int i = 0; i < 2; ++i) {
        int row = wm + i * 16 + l15, sw = row & 7;
        fa[i] = *(const bf16x8*)(As + row * 64 + (((quad + 4 * s) ^ sw) * 8));
      }
#pragma unroll
      for (int j = 0; j < 4; ++j) {
        int row = wn + j * 16 + l15, sw = row & 7;
        bf16x8 fb = *(const bf16x8*)(Bs + row * 64 + (((quad + 4 * s) ^ sw) * 8));
#pragma unroll
        for (int i = 0; i < 2; ++i)
          acc[j][i] = __builtin_amdgcn_mfma_f32_16x16x32_bf16(fb, fa[i], acc[j][i], 0, 0, 0);
      }
    }
    __syncthreads();
  }

  // epilogue (swapped): regs = 4 consecutive n -> float4 stores + float4 bias
#pragma unroll
  for (int j = 0; j < 4; ++j)
#pragma unroll
    for (int i = 0; i < 2; ++i) {
      int n = n0 + wn + j * 16 + quad * 4;
      int m = m0 + wm + i * 16 + l15;
      float4 bv = *(const float4*)(bo + n);
      float4 o;
      o.x = acc[j][i][0] + bv.x; o.y = acc[j][i][1] + bv.y;
      o.z = acc[j][i][2] + bv.z; o.w = acc[j][i][3] + bv.w;
      *(float4*)(out + (size_t)m * DM + n) = o;
    }
}

// ---------------- launch ----------------
extern "C" void kernel_launch(void* const* d_in, const int* in_sizes, int n_in,
                              void* d_out, int out_size, void* d_ws, size_t ws_size,
                              hipStream_t stream) {
  const float* x  = (const float*)d_in[0];
  const float* Wq = (const float*)d_in[1];
  const float* Wk = (const float*)d_in[2];
  const float* Wv = (const float*)d_in[3];
  const float* Wo = (const float*)d_in[4];
  const float* bo = (const float*)d_in[5];
  float* out = (float*)d_out;

  unsigned short* ws = (unsigned short*)d_ws;
  // bf16 workspace: [x(4M) | Wq Wk Wv (3M) | Wo(1M) | Q(4M) | K(4M) | V^T(4M)]; ctx aliases x.
  unsigned short* xb   = ws;
  unsigned short* ctx  = ws;
  unsigned short* wcat = ws + (size_t)MT * DM;
  unsigned short* wob  = wcat + (size_t)3 * DM * DM;
  unsigned short* qb   = wob + (size_t)DM * DM;
  unsigned short* kb   = qb + (size_t)MT * DM;
  unsigned short* vtb  = kb + (size_t)MT * DM;

  int total8 = (MT * DM + 4 * DM * DM) / 8;   // 1M chunks of 8 floats
  cvt_all<<<total8 / 256, 256, 0, stream>>>(x, Wq, Wk, Wv, Wo, ws);

  gemm_qkv<<<dim3(32, 24), 128, 0, stream>>>(xb, wcat, qb, kb, vtb);
  attn_kernel<<<dim3(16, NH, NB), 512, 0, stream>>>(qb, kb, vtb, ctx);
  gemm_out<<<dim3(64, 8), 256, 0, stream>>>(ctx, wob, bo, out);
}